// Round 1
// baseline (420.291 us; speedup 1.0000x reference)
//
#include <hip/hip_runtime.h>

#define EPS_F 1e-8f

typedef float  f32x4  __attribute__((ext_vector_type(4)));
typedef __bf16 bf16x8 __attribute__((ext_vector_type(8)));
typedef unsigned short u16x4 __attribute__((ext_vector_type(4)));

// round-to-nearest-even f32 -> bf16 (inputs are finite; no NaN handling needed)
__device__ inline unsigned short f2bf(float x) {
  unsigned int u = __float_as_uint(x);
  u += 0x7fffu + ((u >> 16) & 1u);
  return (unsigned short)(u >> 16);
}

__global__ __launch_bounds__(256) void hproto_kernel(
    const float* __restrict__ emb, const float* __restrict__ proto,
    float* __restrict__ out)
{
  constexpr int CD = 128;   // feature dim
  constexpr int KP = 512;   // #prototypes
  constexpr int BM = 128;   // rows per block
  constexpr int BN = 128;   // prototype chunk

  __shared__ unsigned short sA[BM * CD];  // bf16 bits, XOR-swizzled
  __shared__ unsigned short sB[BN * CD];
  __shared__ float rne[BM];               // 1/max(||e_row||, eps)
  __shared__ float rnp[BN];               // 1/max(||p_row||, eps), per chunk

  const int tid  = threadIdx.x;
  const int lane = tid & 63;
  const int wave = tid >> 6;
  const long brow = (long)blockIdx.x * BM;

  // Stage 128x128 f32 rows -> swizzled bf16 LDS tile; fused row-norm reduce.
  auto stage = [&](const float* __restrict__ src, unsigned short* dst, float* rn) {
    const float4* s4 = (const float4*)src;
    #pragma unroll
    for (int s = 0; s < 16; ++s) {
      int f  = s * 256 + tid;   // float4 index within tile (4096 total)
      int r  = f >> 5;          // row 0..127 (each row = 32 float4s)
      int c4 = f & 31;
      float4 v = s4[f];
      float ss = v.x*v.x + v.y*v.y + v.z*v.z + v.w*v.w;
      // 32-lane group (t&31 == c4) covers exactly row r -> butterfly reduce
      #pragma unroll
      for (int m = 16; m >= 1; m >>= 1) ss += __shfl_xor(ss, m);
      if ((tid & 31) == 0) rn[r] = 1.0f / fmaxf(sqrtf(ss), EPS_F);
      u16x4 b;
      b[0] = f2bf(v.x); b[1] = f2bf(v.y); b[2] = f2bf(v.z); b[3] = f2bf(v.w);
      int idx = (r * CD + c4 * 4) ^ ((r & 7) << 3);   // XOR-swizzle (shorts)
      *(u16x4*)&dst[idx] = b;
    }
  };

  stage(emb + brow * CD, sA, rne);
  stage(proto, sB, rnp);        // chunk 0
  __syncthreads();

  const int wr = (wave >> 1) * 64;   // wave's row offset in tile
  const int wc = (wave & 1) * 64;    // wave's col offset in chunk

  for (int c = 0; c < 4; ++c) {
    f32x4 acc[4][4];
    #pragma unroll
    for (int m = 0; m < 4; ++m)
      #pragma unroll
      for (int n = 0; n < 4; ++n) acc[m][n] = f32x4{0.f, 0.f, 0.f, 0.f};

    #pragma unroll
    for (int kk = 0; kk < 4; ++kk) {
      const int k0 = kk * 32 + (lane >> 4) * 8;
      bf16x8 af[4], bfr[4];
      #pragma unroll
      for (int m = 0; m < 4; ++m) {
        int row = wr + m * 16 + (lane & 15);
        int idx = (row * CD + k0) ^ ((row & 7) << 3);
        af[m] = *(const bf16x8*)&sA[idx];
      }
      #pragma unroll
      for (int n = 0; n < 4; ++n) {
        int col = wc + n * 16 + (lane & 15);
        int idx = (col * CD + k0) ^ ((col & 7) << 3);
        bfr[n] = *(const bf16x8*)&sB[idx];
      }
      #pragma unroll
      for (int m = 0; m < 4; ++m)
        #pragma unroll
        for (int n = 0; n < 4; ++n)
          acc[m][n] = __builtin_amdgcn_mfma_f32_16x16x32_bf16(af[m], bfr[n], acc[m][n], 0, 0, 0);
    }

    // Epilogue: cos = acc * rne[row] * rnp[col]; out = -(1-cos)^2
    #pragma unroll
    for (int m = 0; m < 4; ++m) {
      float re[4];
      #pragma unroll
      for (int j = 0; j < 4; ++j) re[j] = rne[wr + m * 16 + (lane >> 4) * 4 + j];
      #pragma unroll
      for (int n = 0; n < 4; ++n) {
        float rp = rnp[wc + n * 16 + (lane & 15)];
        long col = (long)c * BN + wc + n * 16 + (lane & 15);
        #pragma unroll
        for (int j = 0; j < 4; ++j) {
          long row = brow + wr + m * 16 + (lane >> 4) * 4 + j;
          float cs = acc[m][n][j] * re[j] * rp;
          float d  = 1.0f - cs;
          out[row * KP + col] = -(d * d);
        }
      }
    }

    if (c < 3) {
      __syncthreads();                              // all waves done with sB/rnp
      stage(proto + (long)(c + 1) * BN * CD, sB, rnp);
      __syncthreads();                              // staged before next compute
    }
  }
}

extern "C" void kernel_launch(void* const* d_in, const int* in_sizes, int n_in,
                              void* d_out, int out_size, void* d_ws, size_t ws_size,
                              hipStream_t stream) {
  const float* emb   = (const float*)d_in[0];
  const float* proto = (const float*)d_in[1];
  float* out = (float*)d_out;
  const int C = 128;
  const int N = in_sizes[0] / C;      // 131072
  hproto_kernel<<<N / 128, 256, 0, stream>>>(emb, proto, out);
}

// Round 2
// 342.819 us; speedup vs baseline: 1.2260x; 1.2260x over previous
//
#include <hip/hip_runtime.h>

#define EPS_F 1e-8f

typedef float  f32x4  __attribute__((ext_vector_type(4)));
typedef __bf16 bf16x8 __attribute__((ext_vector_type(8)));
typedef unsigned short u16x4 __attribute__((ext_vector_type(4)));

// round-to-nearest-even f32 -> bf16 bits (inputs finite; no NaN handling)
__device__ inline unsigned short f2bf(float x) {
  unsigned int u = __float_as_uint(x);
  u += 0x7fffu + ((u >> 16) & 1u);
  return (unsigned short)(u >> 16);
}

// Pre-kernel: normalize each prototype row to unit length, store bf16 bits.
// Bn[k*128 + c] = bf16(proto[k][c] / max(||proto[k]||, eps))
__global__ __launch_bounds__(256) void proto_norm_kernel(
    const float* __restrict__ proto, unsigned short* __restrict__ Bn)
{
  const int tid = threadIdx.x;
  const int g   = tid & 31;                     // lane within 32-group (one row)
  const int row = blockIdx.x * 8 + (tid >> 5);
  const float4 v = *(const float4*)&proto[row * 128 + g * 4];
  float ss = v.x*v.x + v.y*v.y + v.z*v.z + v.w*v.w;
  #pragma unroll
  for (int m = 16; m >= 1; m >>= 1) ss += __shfl_xor(ss, m);
  const float rn = 1.0f / fmaxf(sqrtf(ss), EPS_F);
  u16x4 b;
  b[0] = f2bf(v.x * rn); b[1] = f2bf(v.y * rn);
  b[2] = f2bf(v.z * rn); b[3] = f2bf(v.w * rn);
  *(u16x4*)&Bn[row * 128 + g * 4] = b;
}

__global__ __launch_bounds__(256) void hproto_kernel(
    const float* __restrict__ emb, const unsigned short* __restrict__ Bn,
    float* __restrict__ out)
{
  constexpr int CD = 128;   // feature dim
  constexpr int KP = 512;   // #prototypes
  constexpr int BM = 128;   // rows per block

  __shared__ unsigned short sA[BM * CD];  // bf16 bits, XOR-swizzled
  __shared__ float rne[BM];               // 1/max(||e_row||, eps)

  const int tid  = threadIdx.x;
  const int lane = tid & 63;
  const int wave = tid >> 6;
  const long brow = (long)blockIdx.x * BM;

  // Stage 128x128 f32 embedding rows -> swizzled bf16 LDS; fused row norms.
  {
    const float4* s4 = (const float4*)(emb + brow * CD);
    #pragma unroll
    for (int s = 0; s < 16; ++s) {
      int f  = s * 256 + tid;   // float4 index within tile
      int r  = f >> 5;          // row (32 float4 per row)
      int c4 = f & 31;
      float4 v = s4[f];
      float ss = v.x*v.x + v.y*v.y + v.z*v.z + v.w*v.w;
      #pragma unroll
      for (int m = 16; m >= 1; m >>= 1) ss += __shfl_xor(ss, m);
      if ((tid & 31) == 0) rne[r] = 1.0f / fmaxf(sqrtf(ss), EPS_F);
      u16x4 b;
      b[0] = f2bf(v.x); b[1] = f2bf(v.y); b[2] = f2bf(v.z); b[3] = f2bf(v.w);
      int idx = (r * CD + c4 * 4) ^ ((r & 7) << 3);   // XOR-swizzle (shorts)
      *(u16x4*)&sA[idx] = b;
    }
  }
  __syncthreads();   // the ONLY barrier

  const int wr = (wave >> 1) * 64;   // wave row offset in tile
  const int wc = (wave & 1) * 64;    // wave col offset in 128-col chunk
  const int hi = lane >> 4;
  const int lo = lane & 15;

  // Hoist per-thread row scales (broadcast ds_read_b128, conflict-free).
  f32x4 re[4];
  #pragma unroll
  for (int m = 0; m < 4; ++m)
    re[m] = *(const f32x4*)&rne[wr + m * 16 + hi * 4];

  float* const obase = out + (brow + wr + hi * 4) * KP + wc + lo;

  #pragma unroll 1
  for (int c = 0; c < 4; ++c) {
    // All 16 B fragments for this 128-col chunk, straight from L2-resident Bn.
    bf16x8 bfr[4][4];   // [kk][n]
    #pragma unroll
    for (int n = 0; n < 4; ++n) {
      const unsigned short* bp = Bn + (c * 128 + wc + n * 16 + lo) * CD + hi * 8;
      #pragma unroll
      for (int kk = 0; kk < 4; ++kk)
        bfr[kk][n] = *(const bf16x8*)(bp + kk * 32);
    }

    f32x4 acc[4][4];
    #pragma unroll
    for (int m = 0; m < 4; ++m)
      #pragma unroll
      for (int n = 0; n < 4; ++n) acc[m][n] = f32x4{0.f, 0.f, 0.f, 0.f};

    #pragma unroll
    for (int kk = 0; kk < 4; ++kk) {
      const int k0 = kk * 32 + hi * 8;
      bf16x8 af[4];
      #pragma unroll
      for (int m = 0; m < 4; ++m) {
        int row = wr + m * 16 + lo;
        int idx = (row * CD + k0) ^ ((row & 7) << 3);
        af[m] = *(const bf16x8*)&sA[idx];
      }
      #pragma unroll
      for (int m = 0; m < 4; ++m)
        #pragma unroll
        for (int n = 0; n < 4; ++n)
          acc[m][n] = __builtin_amdgcn_mfma_f32_16x16x32_bf16(af[m], bfr[kk][n], acc[m][n], 0, 0, 0);
    }

    // Epilogue: cos = acc * rne[row]; out = -(1-cos)^2. Nontemporal stores.
    float* const oc = obase + c * 128;
    #pragma unroll
    for (int m = 0; m < 4; ++m) {
      #pragma unroll
      for (int j = 0; j < 4; ++j) {
        float* orow = oc + (long)(m * 16 + j) * KP;
        #pragma unroll
        for (int n = 0; n < 4; ++n) {
          float cs = acc[m][n][j] * re[m][j];
          float d  = 1.0f - cs;
          __builtin_nontemporal_store(-(d * d), orow + n * 16);
        }
      }
    }
  }
}

extern "C" void kernel_launch(void* const* d_in, const int* in_sizes, int n_in,
                              void* d_out, int out_size, void* d_ws, size_t ws_size,
                              hipStream_t stream) {
  const float* emb   = (const float*)d_in[0];
  const float* proto = (const float*)d_in[1];
  float* out = (float*)d_out;
  unsigned short* Bn = (unsigned short*)d_ws;   // 512*128*2 = 128 KB scratch
  const int C = 128;
  const int N = in_sizes[0] / C;   // 131072
  const int K = in_sizes[1] / C;   // 512
  proto_norm_kernel<<<K / 8, 256, 0, stream>>>(proto, Bn);
  hproto_kernel<<<N / 128, 256, 0, stream>>>(emb, Bn, out);
}